// Round 3
// baseline (202.276 us; speedup 1.0000x reference)
//
#include <hip/hip_runtime.h>
#include <hip/hip_bf16.h>

#define D 64

typedef unsigned int   u32;
typedef unsigned short u16;

__device__ __forceinline__ u16 f32_to_bf16_rn(float f) {
  u32 u = __float_as_uint(f);
  u32 r = (u + 0x7FFFu + ((u >> 16) & 1u)) >> 16;   // round-to-nearest-even
  return (u16)r;
}

// Kernel A: quantize track_emb rows to int8 (per-row scale in separate table).
// 16 lanes per row, each handles 4 floats -> 4 int8 packed in one u32.
__global__ void __launch_bounds__(256) quant_emb_kernel(
    const float* __restrict__ emb,
    u32* __restrict__ embq,        // [T,16] u32 = 64 B/row
    float* __restrict__ scales,    // [T]
    int T) {
  int tid = blockIdx.x * blockDim.x + threadIdx.x;
  int t = tid >> 4;
  int l = tid & 15;
  if (t >= T) return;
  float4 v = *(const float4*)(emb + (size_t)t * D + l * 4);
  float m = fmaxf(fmaxf(fabsf(v.x), fabsf(v.y)), fmaxf(fabsf(v.z), fabsf(v.w)));
  m = fmaxf(m, __shfl_xor(m, 1, 64));
  m = fmaxf(m, __shfl_xor(m, 2, 64));
  m = fmaxf(m, __shfl_xor(m, 4, 64));
  m = fmaxf(m, __shfl_xor(m, 8, 64));
  float r = (m > 0.f) ? 127.f / m : 0.f;
  int q0 = __float2int_rn(v.x * r);
  int q1 = __float2int_rn(v.y * r);
  int q2 = __float2int_rn(v.z * r);
  int q3 = __float2int_rn(v.w * r);
  u32 w = (u32)(q0 & 0xFF) | ((u32)(q1 & 0xFF) << 8) |
          ((u32)(q2 & 0xFF) << 16) | ((u32)(q3 & 0xFF) << 24);
  embq[(size_t)t * 16 + l] = w;
  if (l == 0) scales[t] = m * (1.f / 127.f);
}

// Kernel B: ph[p][:] = bf16(0.5*(emb[s0][:] + emb[s1][:]))  (reads f32 emb)
__global__ void __launch_bounds__(256) ph_build_bf16_kernel(
    const float* __restrict__ track_emb,
    const int* __restrict__ sampled,   // [P,2]
    u16* __restrict__ ph,              // [P,D] bf16
    int P) {
  int tid = blockIdx.x * blockDim.x + threadIdx.x;
  int p = tid >> 4;
  int l = tid & 15;
  if (p >= P) return;
  int s0 = sampled[2 * p + 0];
  int s1 = sampled[2 * p + 1];
  const float4 a = *(const float4*)(track_emb + (size_t)s0 * D + l * 4);
  const float4 b = *(const float4*)(track_emb + (size_t)s1 * D + l * 4);
  uint2 o;
  o.x = (u32)f32_to_bf16_rn(0.5f * (a.x + b.x)) |
        ((u32)f32_to_bf16_rn(0.5f * (a.y + b.y)) << 16);
  o.y = (u32)f32_to_bf16_rn(0.5f * (a.z + b.z)) |
        ((u32)f32_to_bf16_rn(0.5f * (a.w + b.w)) << 16);
  *(uint2*)(ph + (size_t)p * D + l * 4) = o;
}

// Kernel C: out[e] = scales[dst] * sum_i q_emb[dst][i] * ph[src][i]
// 8 lanes per edge: each lane loads 8 int8 (uint2) + 8 bf16 (uint4).
__global__ void __launch_bounds__(256) edge_score_q8_kernel(
    const u16* __restrict__ ph,
    const u32* __restrict__ embq,
    const float* __restrict__ scales,
    const int* __restrict__ esrc,
    const int* __restrict__ edst,
    float* __restrict__ out,
    int E) {
  long tid = (long)blockIdx.x * blockDim.x + threadIdx.x;
  int e = (int)(tid >> 3);
  int l = (int)(tid & 7);
  if (e >= E) return;
  int s = esrc[e];
  int d = edst[e];
  const uint2 qa = *(const uint2*)(embq + (size_t)d * 16 + l * 2);
  const uint4 pv = *(const uint4*)(ph + (size_t)s * D + l * 8);
  const u32 qw[2] = {qa.x, qa.y};
  const u32 pw[4] = {pv.x, pv.y, pv.z, pv.w};
  float acc = 0.f;
#pragma unroll
  for (int k = 0; k < 2; ++k) {
    u32 q = qw[k];
    float f0 = (float)((int)(q << 24) >> 24);
    float f1 = (float)((int)(q << 16) >> 24);
    float f2 = (float)((int)(q << 8) >> 24);
    float f3 = (float)((int)q >> 24);
    u32 p0 = pw[2 * k], p1 = pw[2 * k + 1];
    float g0 = __uint_as_float(p0 << 16);
    float g1 = __uint_as_float(p0 & 0xFFFF0000u);
    float g2 = __uint_as_float(p1 << 16);
    float g3 = __uint_as_float(p1 & 0xFFFF0000u);
    acc = fmaf(f0, g0, acc);
    acc = fmaf(f1, g1, acc);
    acc = fmaf(f2, g2, acc);
    acc = fmaf(f3, g3, acc);
  }
  acc += __shfl_xor(acc, 1, 64);
  acc += __shfl_xor(acc, 2, 64);
  acc += __shfl_xor(acc, 4, 64);
  if (l == 0) out[e] = acc * scales[d];
}

// ---------------- f32 fallback (ws too small) ----------------

__global__ void __launch_bounds__(256) ph_build_f32_kernel(
    const float* __restrict__ track_emb, const int* __restrict__ sampled,
    float* __restrict__ ph, int P) {
  int tid = blockIdx.x * blockDim.x + threadIdx.x;
  int p = tid >> 4, l = tid & 15;
  if (p >= P) return;
  int s0 = sampled[2 * p + 0], s1 = sampled[2 * p + 1];
  const float4 a = *(const float4*)(track_emb + (size_t)s0 * D + l * 4);
  const float4 b = *(const float4*)(track_emb + (size_t)s1 * D + l * 4);
  float4 r;
  r.x = 0.5f * (a.x + b.x); r.y = 0.5f * (a.y + b.y);
  r.z = 0.5f * (a.z + b.z); r.w = 0.5f * (a.w + b.w);
  *(float4*)(ph + (size_t)p * D + l * 4) = r;
}

__global__ void __launch_bounds__(256) edge_score_f32_kernel(
    const float* __restrict__ ph, const float* __restrict__ track_emb,
    const int* __restrict__ esrc, const int* __restrict__ edst,
    float* __restrict__ out, int E) {
  int tid = blockIdx.x * blockDim.x + threadIdx.x;
  int e = tid >> 4, l = tid & 15;
  if (e >= E) return;
  int s = esrc[e], d = edst[e];
  const float4 a = *(const float4*)(ph + (size_t)s * D + l * 4);
  const float4 b = *(const float4*)(track_emb + (size_t)d * D + l * 4);
  float v = a.x * b.x + a.y * b.y + a.z * b.z + a.w * b.w;
  v += __shfl_xor(v, 1, 64);
  v += __shfl_xor(v, 2, 64);
  v += __shfl_xor(v, 4, 64);
  if (l == 0) out[e] = v;
}

extern "C" void kernel_launch(void* const* d_in, const int* in_sizes, int n_in,
                              void* d_out, int out_size, void* d_ws, size_t ws_size,
                              hipStream_t stream) {
  const float* track_emb = (const float*)d_in[0];   // [T, 64] f32
  const int*   edge_src  = (const int*)d_in[1];     // [E]
  const int*   edge_dst  = (const int*)d_in[2];     // [E]
  const int*   sampled   = (const int*)d_in[3];     // [P, 2]
  float* out = (float*)d_out;                       // [E] f32

  const int E = in_sizes[1];
  const int P = in_sizes[3] / 2;
  const int T = in_sizes[0] / D;

  const size_t embq_bytes   = (size_t)T * 16 * sizeof(u32);   // 32 MB
  const size_t scales_bytes = (size_t)T * sizeof(float);      // 2 MB
  const size_t ph_bytes     = (size_t)P * D * sizeof(u16);    // 12.8 MB

  if (ws_size >= embq_bytes + scales_bytes + ph_bytes) {
    u32*   embq   = (u32*)d_ws;
    float* scales = (float*)((char*)d_ws + embq_bytes);
    u16*   ph     = (u16*)((char*)d_ws + embq_bytes + scales_bytes);

    // A: quantize track_emb -> int8 + per-row scale
    {
      long t = (long)T * 16;
      int blocks = (int)((t + 255) / 256);
      quant_emb_kernel<<<blocks, 256, 0, stream>>>(track_emb, embq, scales, T);
    }
    // B: build ph (bf16)
    {
      long t = (long)P * 16;
      int blocks = (int)((t + 255) / 256);
      ph_build_bf16_kernel<<<blocks, 256, 0, stream>>>(track_emb, sampled, ph, P);
    }
    // C: edge scores
    {
      long t = (long)E * 8;
      int blocks = (int)((t + 255) / 256);
      edge_score_q8_kernel<<<blocks, 256, 0, stream>>>(ph, embq, scales,
                                                       edge_src, edge_dst, out, E);
    }
  } else {
    // fallback: f32 path
    float* ph = (float*)d_ws;
    {
      long t = (long)P * 16;
      int blocks = (int)((t + 255) / 256);
      ph_build_f32_kernel<<<blocks, 256, 0, stream>>>(track_emb, sampled, ph, P);
    }
    {
      long t = (long)E * 16;
      int blocks = (int)((t + 255) / 256);
      edge_score_f32_kernel<<<blocks, 256, 0, stream>>>(ph, track_emb, edge_src,
                                                        edge_dst, out, E);
    }
  }
}

// Round 4
// 201.946 us; speedup vs baseline: 1.0016x; 1.0016x over previous
//
#include <hip/hip_runtime.h>
#include <hip/hip_bf16.h>

#define D 64

typedef unsigned int   u32;
typedef unsigned short u16;
typedef float f32x4 __attribute__((ext_vector_type(4)));
typedef u32   u32x4 __attribute__((ext_vector_type(4)));

// ---------------- int8 path ----------------
// embq: [T][16] u32 (64 int8 per row, 64 B = 1 cache line), escale: [T] f32
// phq:  [P][16] u32, pscale: [P] f32

// Kernel A: quantize track_emb rows to int8. 16 lanes/row, float4 each.
// f32 emb is streamed ONCE per call with non-temporal loads (don't pollute
// L2/L3 -- the gather working set must stay resident).
__global__ void __launch_bounds__(256) quant_emb_kernel(
    const float* __restrict__ emb,
    u32* __restrict__ embq,
    float* __restrict__ escale,
    int T) {
  int tid = blockIdx.x * blockDim.x + threadIdx.x;
  int t = tid >> 4;
  int l = tid & 15;
  if (t >= T) return;
  f32x4 v = __builtin_nontemporal_load(
      (const f32x4*)(emb + (size_t)t * D) + l);
  float m = fmaxf(fmaxf(fabsf(v.x), fabsf(v.y)), fmaxf(fabsf(v.z), fabsf(v.w)));
  m = fmaxf(m, __shfl_xor(m, 1, 64));
  m = fmaxf(m, __shfl_xor(m, 2, 64));
  m = fmaxf(m, __shfl_xor(m, 4, 64));
  m = fmaxf(m, __shfl_xor(m, 8, 64));
  float r = (m > 0.f) ? 127.f / m : 0.f;
  int q0 = __float2int_rn(v.x * r);
  int q1 = __float2int_rn(v.y * r);
  int q2 = __float2int_rn(v.z * r);
  int q3 = __float2int_rn(v.w * r);
  u32 w = (u32)(q0 & 0xFF) | ((u32)(q1 & 0xFF) << 8) |
          ((u32)(q2 & 0xFF) << 16) | ((u32)(q3 & 0xFF) << 24);
  embq[(size_t)t * 16 + l] = w;
  if (l == 0) escale[t] = (m > 0.f) ? m / 127.f : 0.f;
}

// Kernel B: phq[p] = int8( 0.5*(deq(embq[s0]) + deq(embq[s1])) ), 4 lanes/row.
// Reads the int8 table (12.8 MB of gathers) instead of f32 emb (51 MB).
__global__ void __launch_bounds__(256) ph_build_q8_kernel(
    const u32* __restrict__ embq,
    const float* __restrict__ escale,
    const int* __restrict__ sampled,   // [P,2]
    u32* __restrict__ phq,
    float* __restrict__ pscale,
    int P) {
  int tid = blockIdx.x * blockDim.x + threadIdx.x;
  int p = tid >> 2;
  int l = tid & 3;
  if (p >= P) return;
  int s0 = sampled[2 * p + 0];
  int s1 = sampled[2 * p + 1];
  u32x4 q0 = *(const u32x4*)(embq + (size_t)s0 * 16 + l * 4);
  u32x4 q1 = *(const u32x4*)(embq + (size_t)s1 * 16 + l * 4);
  float c0 = 0.5f * escale[s0];
  float c1 = 0.5f * escale[s1];
  float f[16];
#pragma unroll
  for (int k = 0; k < 4; ++k) {
    u32 a = q0[k], b = q1[k];
    f[4 * k + 0] = c0 * (float)((int)(a << 24) >> 24) + c1 * (float)((int)(b << 24) >> 24);
    f[4 * k + 1] = c0 * (float)((int)(a << 16) >> 24) + c1 * (float)((int)(b << 16) >> 24);
    f[4 * k + 2] = c0 * (float)((int)(a << 8) >> 24)  + c1 * (float)((int)(b << 8) >> 24);
    f[4 * k + 3] = c0 * (float)((int)a >> 24)         + c1 * (float)((int)b >> 24);
  }
  float m = 0.f;
#pragma unroll
  for (int i = 0; i < 16; ++i) m = fmaxf(m, fabsf(f[i]));
  m = fmaxf(m, __shfl_xor(m, 1, 64));
  m = fmaxf(m, __shfl_xor(m, 2, 64));
  float r = (m > 0.f) ? 127.f / m : 0.f;
  u32x4 w;
#pragma unroll
  for (int k = 0; k < 4; ++k) {
    int a0 = __float2int_rn(f[4 * k + 0] * r);
    int a1 = __float2int_rn(f[4 * k + 1] * r);
    int a2 = __float2int_rn(f[4 * k + 2] * r);
    int a3 = __float2int_rn(f[4 * k + 3] * r);
    w[k] = (u32)(a0 & 0xFF) | ((u32)(a1 & 0xFF) << 8) |
           ((u32)(a2 & 0xFF) << 16) | ((u32)(a3 & 0xFF) << 24);
  }
  *(u32x4*)(phq + (size_t)p * 16 + l * 4) = w;
  if (l == 0) pscale[p] = (m > 0.f) ? m / 127.f : 0.f;
}

// Kernel C: out[e] = pscale[s]*escale[d] * sum_i phq[s][i]*embq[d][i]
// 4 lanes/edge, each lane: uint4 (16 int8) of both rows, exact int32 dot.
__global__ void __launch_bounds__(256) edge_score_q8q8_kernel(
    const u32* __restrict__ phq,
    const float* __restrict__ pscale,
    const u32* __restrict__ embq,
    const float* __restrict__ escale,
    const int* __restrict__ esrc,
    const int* __restrict__ edst,
    float* __restrict__ out,
    int E) {
  long tid = (long)blockIdx.x * blockDim.x + threadIdx.x;
  int e = (int)(tid >> 2);
  int l = (int)(tid & 3);
  if (e >= E) return;
  int s = __builtin_nontemporal_load(esrc + e);
  int d = __builtin_nontemporal_load(edst + e);
  u32x4 qp = *(const u32x4*)(phq  + (size_t)s * 16 + l * 4);
  u32x4 qe = *(const u32x4*)(embq + (size_t)d * 16 + l * 4);
  int acc = 0;
#pragma unroll
  for (int k = 0; k < 4; ++k) {
    u32 a = qp[k], b = qe[k];
    acc += ((int)(a << 24) >> 24) * ((int)(b << 24) >> 24);
    acc += ((int)(a << 16) >> 24) * ((int)(b << 16) >> 24);
    acc += ((int)(a << 8) >> 24)  * ((int)(b << 8) >> 24);
    acc += ((int)a >> 24)         * ((int)b >> 24);
  }
  acc += __shfl_xor(acc, 1, 64);
  acc += __shfl_xor(acc, 2, 64);
  if (l == 0) {
    float o = (float)acc * pscale[s] * escale[d];
    __builtin_nontemporal_store(o, out + e);
  }
}

// ---------------- f32 fallback (ws too small) ----------------

__global__ void __launch_bounds__(256) ph_build_f32_kernel(
    const float* __restrict__ track_emb, const int* __restrict__ sampled,
    float* __restrict__ ph, int P) {
  int tid = blockIdx.x * blockDim.x + threadIdx.x;
  int p = tid >> 4, l = tid & 15;
  if (p >= P) return;
  int s0 = sampled[2 * p + 0], s1 = sampled[2 * p + 1];
  const float4 a = *(const float4*)(track_emb + (size_t)s0 * D + l * 4);
  const float4 b = *(const float4*)(track_emb + (size_t)s1 * D + l * 4);
  float4 r;
  r.x = 0.5f * (a.x + b.x); r.y = 0.5f * (a.y + b.y);
  r.z = 0.5f * (a.z + b.z); r.w = 0.5f * (a.w + b.w);
  *(float4*)(ph + (size_t)p * D + l * 4) = r;
}

__global__ void __launch_bounds__(256) edge_score_f32_kernel(
    const float* __restrict__ ph, const float* __restrict__ track_emb,
    const int* __restrict__ esrc, const int* __restrict__ edst,
    float* __restrict__ out, int E) {
  int tid = blockIdx.x * blockDim.x + threadIdx.x;
  int e = tid >> 4, l = tid & 15;
  if (e >= E) return;
  int s = esrc[e], d = edst[e];
  const float4 a = *(const float4*)(ph + (size_t)s * D + l * 4);
  const float4 b = *(const float4*)(track_emb + (size_t)d * D + l * 4);
  float v = a.x * b.x + a.y * b.y + a.z * b.z + a.w * b.w;
  v += __shfl_xor(v, 1, 64);
  v += __shfl_xor(v, 2, 64);
  v += __shfl_xor(v, 4, 64);
  if (l == 0) out[e] = v;
}

extern "C" void kernel_launch(void* const* d_in, const int* in_sizes, int n_in,
                              void* d_out, int out_size, void* d_ws, size_t ws_size,
                              hipStream_t stream) {
  const float* track_emb = (const float*)d_in[0];   // [T, 64] f32
  const int*   edge_src  = (const int*)d_in[1];     // [E]
  const int*   edge_dst  = (const int*)d_in[2];     // [E]
  const int*   sampled   = (const int*)d_in[3];     // [P, 2]
  float* out = (float*)d_out;                       // [E] f32

  const int E = in_sizes[1];
  const int P = in_sizes[3] / 2;
  const int T = in_sizes[0] / D;

  const size_t embq_bytes   = (size_t)T * 16 * sizeof(u32);   // 32 MB
  const size_t escale_bytes = (size_t)T * sizeof(float);      // 2 MB
  const size_t phq_bytes    = (size_t)P * 16 * sizeof(u32);   // 6.4 MB
  const size_t pscale_bytes = (size_t)P * sizeof(float);      // 0.4 MB

  if (ws_size >= embq_bytes + escale_bytes + phq_bytes + pscale_bytes) {
    char* w = (char*)d_ws;
    u32*   embq   = (u32*)w;                       w += embq_bytes;
    float* escale = (float*)w;                     w += escale_bytes;
    u32*   phq    = (u32*)w;                       w += phq_bytes;
    float* pscale = (float*)w;

    // A: quantize track_emb -> int8 + per-row scale (NT streaming read)
    {
      long t = (long)T * 16;
      int blocks = (int)((t + 255) / 256);
      quant_emb_kernel<<<blocks, 256, 0, stream>>>(track_emb, embq, escale, T);
    }
    // B: build phq (int8) from embq
    {
      long t = (long)P * 4;
      int blocks = (int)((t + 255) / 256);
      ph_build_q8_kernel<<<blocks, 256, 0, stream>>>(embq, escale, sampled,
                                                     phq, pscale, P);
    }
    // C: edge scores (1 line per gather side)
    {
      long t = (long)E * 4;
      int blocks = (int)((t + 255) / 256);
      edge_score_q8q8_kernel<<<blocks, 256, 0, stream>>>(
          phq, pscale, embq, escale, edge_src, edge_dst, out, E);
    }
  } else {
    // fallback: f32 path
    float* ph = (float*)d_ws;
    {
      long t = (long)P * 16;
      int blocks = (int)((t + 255) / 256);
      ph_build_f32_kernel<<<blocks, 256, 0, stream>>>(track_emb, sampled, ph, P);
    }
    {
      long t = (long)E * 16;
      int blocks = (int)((t + 255) / 256);
      edge_score_f32_kernel<<<blocks, 256, 0, stream>>>(ph, track_emb, edge_src,
                                                        edge_dst, out, E);
    }
  }
}

// Round 5
// 199.193 us; speedup vs baseline: 1.0155x; 1.0138x over previous
//
#include <hip/hip_runtime.h>
#include <hip/hip_bf16.h>

#define D 64

typedef unsigned int   u32;
typedef unsigned short u16;
typedef float f32x4 __attribute__((ext_vector_type(4)));
typedef u32   u32x4 __attribute__((ext_vector_type(4)));

// ---------------- int8 path ----------------
// embq: [T][16] u32 (64 int8 per row, 64 B = 1 cache line), escale: [T] f32
// phq:  [P][16] u32, pscale: [P] f32
//
// L2 strategy (round 5): the edge kernel's embq gathers (32 MB table, ~0% L2
// hit possible) are NON-TEMPORAL so they allocate evict-first and stop
// thrashing the 4 MiB/XCD L2; phq (6.4 MB) + scales (2.4 MB) stay temporal
// and should become L2-resident.

// Kernel A: quantize track_emb rows to int8. 16 lanes/row, float4 each.
__global__ void __launch_bounds__(256) quant_emb_kernel(
    const float* __restrict__ emb,
    u32* __restrict__ embq,
    float* __restrict__ escale,
    int T) {
  int tid = blockIdx.x * blockDim.x + threadIdx.x;
  int t = tid >> 4;
  int l = tid & 15;
  if (t >= T) return;
  f32x4 v = __builtin_nontemporal_load(
      (const f32x4*)(emb + (size_t)t * D) + l);
  float m = fmaxf(fmaxf(fabsf(v.x), fabsf(v.y)), fmaxf(fabsf(v.z), fabsf(v.w)));
  m = fmaxf(m, __shfl_xor(m, 1, 64));
  m = fmaxf(m, __shfl_xor(m, 2, 64));
  m = fmaxf(m, __shfl_xor(m, 4, 64));
  m = fmaxf(m, __shfl_xor(m, 8, 64));
  float r = (m > 0.f) ? 127.f / m : 0.f;
  int q0 = __float2int_rn(v.x * r);
  int q1 = __float2int_rn(v.y * r);
  int q2 = __float2int_rn(v.z * r);
  int q3 = __float2int_rn(v.w * r);
  u32 w = (u32)(q0 & 0xFF) | ((u32)(q1 & 0xFF) << 8) |
          ((u32)(q2 & 0xFF) << 16) | ((u32)(q3 & 0xFF) << 24);
  embq[(size_t)t * 16 + l] = w;
  if (l == 0) escale[t] = (m > 0.f) ? m / 127.f : 0.f;
}

// Kernel B: phq[p] = int8( 0.5*(deq(embq[s0]) + deq(embq[s1])) ), 4 lanes/row.
__global__ void __launch_bounds__(256) ph_build_q8_kernel(
    const u32* __restrict__ embq,
    const float* __restrict__ escale,
    const int* __restrict__ sampled,   // [P,2]
    u32* __restrict__ phq,
    float* __restrict__ pscale,
    int P) {
  int tid = blockIdx.x * blockDim.x + threadIdx.x;
  int p = tid >> 2;
  int l = tid & 3;
  if (p >= P) return;
  int s0 = sampled[2 * p + 0];
  int s1 = sampled[2 * p + 1];
  u32x4 q0 = *(const u32x4*)(embq + (size_t)s0 * 16 + l * 4);
  u32x4 q1 = *(const u32x4*)(embq + (size_t)s1 * 16 + l * 4);
  float c0 = 0.5f * escale[s0];
  float c1 = 0.5f * escale[s1];
  float f[16];
#pragma unroll
  for (int k = 0; k < 4; ++k) {
    u32 a = q0[k], b = q1[k];
    f[4 * k + 0] = c0 * (float)((int)(a << 24) >> 24) + c1 * (float)((int)(b << 24) >> 24);
    f[4 * k + 1] = c0 * (float)((int)(a << 16) >> 24) + c1 * (float)((int)(b << 16) >> 24);
    f[4 * k + 2] = c0 * (float)((int)(a << 8) >> 24)  + c1 * (float)((int)(b << 8) >> 24);
    f[4 * k + 3] = c0 * (float)((int)a >> 24)         + c1 * (float)((int)b >> 24);
  }
  float m = 0.f;
#pragma unroll
  for (int i = 0; i < 16; ++i) m = fmaxf(m, fabsf(f[i]));
  m = fmaxf(m, __shfl_xor(m, 1, 64));
  m = fmaxf(m, __shfl_xor(m, 2, 64));
  float r = (m > 0.f) ? 127.f / m : 0.f;
  u32x4 w;
#pragma unroll
  for (int k = 0; k < 4; ++k) {
    int a0 = __float2int_rn(f[4 * k + 0] * r);
    int a1 = __float2int_rn(f[4 * k + 1] * r);
    int a2 = __float2int_rn(f[4 * k + 2] * r);
    int a3 = __float2int_rn(f[4 * k + 3] * r);
    w[k] = (u32)(a0 & 0xFF) | ((u32)(a1 & 0xFF) << 8) |
           ((u32)(a2 & 0xFF) << 16) | ((u32)(a3 & 0xFF) << 24);
  }
  *(u32x4*)(phq + (size_t)p * 16 + l * 4) = w;
  if (l == 0) pscale[p] = (m > 0.f) ? m / 127.f : 0.f;
}

// Kernel C: out[e] = pscale[s]*escale[d] * sum_i phq[s][i]*embq[d][i]
// 4 lanes/edge. embq gather is NON-TEMPORAL (evict-first), phq temporal.
__global__ void __launch_bounds__(256) edge_score_q8q8_kernel(
    const u32* __restrict__ phq,
    const float* __restrict__ pscale,
    const u32* __restrict__ embq,
    const float* __restrict__ escale,
    const int* __restrict__ esrc,
    const int* __restrict__ edst,
    float* __restrict__ out,
    int E) {
  long tid = (long)blockIdx.x * blockDim.x + threadIdx.x;
  int e = (int)(tid >> 2);
  int l = (int)(tid & 3);
  if (e >= E) return;
  int s = __builtin_nontemporal_load(esrc + e);
  int d = __builtin_nontemporal_load(edst + e);
  u32x4 qp = *(const u32x4*)(phq + (size_t)s * 16 + l * 4);          // temporal
  u32x4 qe = __builtin_nontemporal_load(
      (const u32x4*)(embq + (size_t)d * 16 + l * 4));                // NT
  int acc = 0;
#pragma unroll
  for (int k = 0; k < 4; ++k) {
    u32 a = qp[k], b = qe[k];
    acc += ((int)(a << 24) >> 24) * ((int)(b << 24) >> 24);
    acc += ((int)(a << 16) >> 24) * ((int)(b << 16) >> 24);
    acc += ((int)(a << 8) >> 24)  * ((int)(b << 8) >> 24);
    acc += ((int)a >> 24)         * ((int)b >> 24);
  }
  acc += __shfl_xor(acc, 1, 64);
  acc += __shfl_xor(acc, 2, 64);
  if (l == 0) {
    float o = (float)acc * pscale[s] * escale[d];
    __builtin_nontemporal_store(o, out + e);
  }
}

// ---------------- f32 fallback (ws too small) ----------------

__global__ void __launch_bounds__(256) ph_build_f32_kernel(
    const float* __restrict__ track_emb, const int* __restrict__ sampled,
    float* __restrict__ ph, int P) {
  int tid = blockIdx.x * blockDim.x + threadIdx.x;
  int p = tid >> 4, l = tid & 15;
  if (p >= P) return;
  int s0 = sampled[2 * p + 0], s1 = sampled[2 * p + 1];
  const float4 a = *(const float4*)(track_emb + (size_t)s0 * D + l * 4);
  const float4 b = *(const float4*)(track_emb + (size_t)s1 * D + l * 4);
  float4 r;
  r.x = 0.5f * (a.x + b.x); r.y = 0.5f * (a.y + b.y);
  r.z = 0.5f * (a.z + b.z); r.w = 0.5f * (a.w + b.w);
  *(float4*)(ph + (size_t)p * D + l * 4) = r;
}

__global__ void __launch_bounds__(256) edge_score_f32_kernel(
    const float* __restrict__ ph, const float* __restrict__ track_emb,
    const int* __restrict__ esrc, const int* __restrict__ edst,
    float* __restrict__ out, int E) {
  int tid = blockIdx.x * blockDim.x + threadIdx.x;
  int e = tid >> 4, l = tid & 15;
  if (e >= E) return;
  int s = esrc[e], d = edst[e];
  const float4 a = *(const float4*)(ph + (size_t)s * D + l * 4);
  const float4 b = *(const float4*)(track_emb + (size_t)d * D + l * 4);
  float v = a.x * b.x + a.y * b.y + a.z * b.z + a.w * b.w;
  v += __shfl_xor(v, 1, 64);
  v += __shfl_xor(v, 2, 64);
  v += __shfl_xor(v, 4, 64);
  if (l == 0) out[e] = v;
}

extern "C" void kernel_launch(void* const* d_in, const int* in_sizes, int n_in,
                              void* d_out, int out_size, void* d_ws, size_t ws_size,
                              hipStream_t stream) {
  const float* track_emb = (const float*)d_in[0];   // [T, 64] f32
  const int*   edge_src  = (const int*)d_in[1];     // [E]
  const int*   edge_dst  = (const int*)d_in[2];     // [E]
  const int*   sampled   = (const int*)d_in[3];     // [P, 2]
  float* out = (float*)d_out;                       // [E] f32

  const int E = in_sizes[1];
  const int P = in_sizes[3] / 2;
  const int T = in_sizes[0] / D;

  const size_t embq_bytes   = (size_t)T * 16 * sizeof(u32);   // 32 MB
  const size_t escale_bytes = (size_t)T * sizeof(float);      // 2 MB
  const size_t phq_bytes    = (size_t)P * 16 * sizeof(u32);   // 6.4 MB
  const size_t pscale_bytes = (size_t)P * sizeof(float);      // 0.4 MB

  if (ws_size >= embq_bytes + escale_bytes + phq_bytes + pscale_bytes) {
    char* w = (char*)d_ws;
    u32*   embq   = (u32*)w;                       w += embq_bytes;
    float* escale = (float*)w;                     w += escale_bytes;
    u32*   phq    = (u32*)w;                       w += phq_bytes;
    float* pscale = (float*)w;

    // A: quantize track_emb -> int8 + per-row scale (NT streaming read)
    {
      long t = (long)T * 16;
      int blocks = (int)((t + 255) / 256);
      quant_emb_kernel<<<blocks, 256, 0, stream>>>(track_emb, embq, escale, T);
    }
    // B: build phq (int8) from embq
    {
      long t = (long)P * 4;
      int blocks = (int)((t + 255) / 256);
      ph_build_q8_kernel<<<blocks, 256, 0, stream>>>(embq, escale, sampled,
                                                     phq, pscale, P);
    }
    // C: edge scores
    {
      long t = (long)E * 4;
      int blocks = (int)((t + 255) / 256);
      edge_score_q8q8_kernel<<<blocks, 256, 0, stream>>>(
          phq, pscale, embq, escale, edge_src, edge_dst, out, E);
    }
  } else {
    // fallback: f32 path
    float* ph = (float*)d_ws;
    {
      long t = (long)P * 16;
      int blocks = (int)((t + 255) / 256);
      ph_build_f32_kernel<<<blocks, 256, 0, stream>>>(track_emb, sampled, ph, P);
    }
    {
      long t = (long)E * 16;
      int blocks = (int)((t + 255) / 256);
      edge_score_f32_kernel<<<blocks, 256, 0, stream>>>(ph, track_emb, edge_src,
                                                        edge_dst, out, E);
    }
  }
}

// Round 6
// 194.410 us; speedup vs baseline: 1.0405x; 1.0246x over previous
//
#include <hip/hip_runtime.h>
#include <hip/hip_bf16.h>

#define D 64

typedef unsigned int   u32;
typedef unsigned short u16;
typedef float f32x4 __attribute__((ext_vector_type(4)));
typedef u32   u32x4 __attribute__((ext_vector_type(4)));

__device__ __forceinline__ u16 f32_to_bf16_rn_bits(float f) {
  u32 u = __float_as_uint(f);
  u32 r = (u + 0x7FFFu + ((u >> 16) & 1u)) >> 16;
  return (u16)r;
}
__device__ __forceinline__ float bf16_bits_to_f32(u16 h) {
  return __uint_as_float((u32)h << 16);
}

// ---------------- int8 path ----------------
// embq: [T][16] u32 (64 int8/row = 1 line), escale: [T] bf16 (1 MB)
// phq:  [P][16] u32 (6.4 MB, the L2-hot table), pscale: [P] bf16 (0.2 MB)
//
// L2 strategy: edge kernel's embq gathers (32 MB, unavoidable misses) use
// sc1+nt (bypass/evict-first past L2) so the 4 MiB/XCD L2 retains phq+scales
// (~7.6 MB hot set). Safe: inter-kernel barrier flushes L2, embq is clean.

// Kernel A: quantize track_emb rows to int8 + per-row bf16 scale.
__global__ void __launch_bounds__(256) quant_emb_kernel(
    const float* __restrict__ emb,
    u32* __restrict__ embq,
    u16* __restrict__ escale,
    int T) {
  int tid = blockIdx.x * blockDim.x + threadIdx.x;
  int t = tid >> 4;
  int l = tid & 15;
  if (t >= T) return;
  f32x4 v = __builtin_nontemporal_load(
      (const f32x4*)(emb + (size_t)t * D) + l);
  float m = fmaxf(fmaxf(fabsf(v.x), fabsf(v.y)), fmaxf(fabsf(v.z), fabsf(v.w)));
  m = fmaxf(m, __shfl_xor(m, 1, 64));
  m = fmaxf(m, __shfl_xor(m, 2, 64));
  m = fmaxf(m, __shfl_xor(m, 4, 64));
  m = fmaxf(m, __shfl_xor(m, 8, 64));
  float r = (m > 0.f) ? 127.f / m : 0.f;
  int q0 = __float2int_rn(v.x * r);
  int q1 = __float2int_rn(v.y * r);
  int q2 = __float2int_rn(v.z * r);
  int q3 = __float2int_rn(v.w * r);
  u32 w = (u32)(q0 & 0xFF) | ((u32)(q1 & 0xFF) << 8) |
          ((u32)(q2 & 0xFF) << 16) | ((u32)(q3 & 0xFF) << 24);
  embq[(size_t)t * 16 + l] = w;
  if (l == 0) escale[t] = f32_to_bf16_rn_bits((m > 0.f) ? m / 127.f : 0.f);
}

// Kernel B: phq[p] = int8( 0.5*(deq(embq[s0]) + deq(embq[s1])) ), 4 lanes/row.
__global__ void __launch_bounds__(256) ph_build_q8_kernel(
    const u32* __restrict__ embq,
    const u16* __restrict__ escale,
    const int* __restrict__ sampled,   // [P,2]
    u32* __restrict__ phq,
    u16* __restrict__ pscale,
    int P) {
  int tid = blockIdx.x * blockDim.x + threadIdx.x;
  int p = tid >> 2;
  int l = tid & 3;
  if (p >= P) return;
  int s0 = sampled[2 * p + 0];
  int s1 = sampled[2 * p + 1];
  u32x4 q0 = *(const u32x4*)(embq + (size_t)s0 * 16 + l * 4);
  u32x4 q1 = *(const u32x4*)(embq + (size_t)s1 * 16 + l * 4);
  float c0 = 0.5f * bf16_bits_to_f32(escale[s0]);
  float c1 = 0.5f * bf16_bits_to_f32(escale[s1]);
  float f[16];
#pragma unroll
  for (int k = 0; k < 4; ++k) {
    u32 a = q0[k], b = q1[k];
    f[4 * k + 0] = c0 * (float)((int)(a << 24) >> 24) + c1 * (float)((int)(b << 24) >> 24);
    f[4 * k + 1] = c0 * (float)((int)(a << 16) >> 24) + c1 * (float)((int)(b << 16) >> 24);
    f[4 * k + 2] = c0 * (float)((int)(a << 8) >> 24)  + c1 * (float)((int)(b << 8) >> 24);
    f[4 * k + 3] = c0 * (float)((int)a >> 24)         + c1 * (float)((int)b >> 24);
  }
  float m = 0.f;
#pragma unroll
  for (int i = 0; i < 16; ++i) m = fmaxf(m, fabsf(f[i]));
  m = fmaxf(m, __shfl_xor(m, 1, 64));
  m = fmaxf(m, __shfl_xor(m, 2, 64));
  float r = (m > 0.f) ? 127.f / m : 0.f;
  u32x4 w;
#pragma unroll
  for (int k = 0; k < 4; ++k) {
    int a0 = __float2int_rn(f[4 * k + 0] * r);
    int a1 = __float2int_rn(f[4 * k + 1] * r);
    int a2 = __float2int_rn(f[4 * k + 2] * r);
    int a3 = __float2int_rn(f[4 * k + 3] * r);
    w[k] = (u32)(a0 & 0xFF) | ((u32)(a1 & 0xFF) << 8) |
           ((u32)(a2 & 0xFF) << 16) | ((u32)(a3 & 0xFF) << 24);
  }
  *(u32x4*)(phq + (size_t)p * 16 + l * 4) = w;
  if (l == 0) pscale[p] = f32_to_bf16_rn_bits((m > 0.f) ? m / 127.f : 0.f);
}

// Kernel C: out[e] = pscale[s]*escale[d] * (phq[s] . embq[d])  [int32 exact dot]
// 4 lanes/edge. embq load: sc1+nt (bypass L2); phq load: temporal (allocate).
__global__ void __launch_bounds__(256) edge_score_q8q8_kernel(
    const u32* __restrict__ phq,
    const u16* __restrict__ pscale,
    const u32* __restrict__ embq,
    const u16* __restrict__ escale,
    const int* __restrict__ esrc,
    const int* __restrict__ edst,
    float* __restrict__ out,
    int E) {
  long tid = (long)blockIdx.x * blockDim.x + threadIdx.x;
  int e = (int)(tid >> 2);
  int l = (int)(tid & 3);
  if (e >= E) return;
  int s = __builtin_nontemporal_load(esrc + e);
  int d = __builtin_nontemporal_load(edst + e);

  const u32* eaddr = embq + (size_t)d * 16 + l * 4;
  u32x4 qe;
  // issue embq gather with L2-bypass flags; do NOT wait yet
  asm volatile("global_load_dwordx4 %0, %1, off sc1 nt"
               : "=&v"(qe) : "v"(eaddr));
  // temporal phq gather overlaps the in-flight embq load
  u32x4 qp = *(const u32x4*)(phq + (size_t)s * 16 + l * 4);
  // drain both; "+v" ties qe's uses to after this point
  asm volatile("s_waitcnt vmcnt(0)" : "+v"(qp), "+v"(qe) :: "memory");
  __builtin_amdgcn_sched_barrier(0);

  int acc = 0;
#if __has_builtin(__builtin_amdgcn_sdot4)
#pragma unroll
  for (int k = 0; k < 4; ++k)
    acc = __builtin_amdgcn_sdot4((int)qp[k], (int)qe[k], acc, false);
#else
#pragma unroll
  for (int k = 0; k < 4; ++k) {
    u32 a = qp[k], b = qe[k];
    acc += ((int)(a << 24) >> 24) * ((int)(b << 24) >> 24);
    acc += ((int)(a << 16) >> 24) * ((int)(b << 16) >> 24);
    acc += ((int)(a << 8) >> 24)  * ((int)(b << 8) >> 24);
    acc += ((int)a >> 24)         * ((int)b >> 24);
  }
#endif
  acc += __shfl_xor(acc, 1, 64);
  acc += __shfl_xor(acc, 2, 64);
  if (l == 0) {
    float o = (float)acc * bf16_bits_to_f32(pscale[s]) * bf16_bits_to_f32(escale[d]);
    __builtin_nontemporal_store(o, out + e);
  }
}

// ---------------- f32 fallback (ws too small) ----------------

__global__ void __launch_bounds__(256) ph_build_f32_kernel(
    const float* __restrict__ track_emb, const int* __restrict__ sampled,
    float* __restrict__ ph, int P) {
  int tid = blockIdx.x * blockDim.x + threadIdx.x;
  int p = tid >> 4, l = tid & 15;
  if (p >= P) return;
  int s0 = sampled[2 * p + 0], s1 = sampled[2 * p + 1];
  const float4 a = *(const float4*)(track_emb + (size_t)s0 * D + l * 4);
  const float4 b = *(const float4*)(track_emb + (size_t)s1 * D + l * 4);
  float4 r;
  r.x = 0.5f * (a.x + b.x); r.y = 0.5f * (a.y + b.y);
  r.z = 0.5f * (a.z + b.z); r.w = 0.5f * (a.w + b.w);
  *(float4*)(ph + (size_t)p * D + l * 4) = r;
}

__global__ void __launch_bounds__(256) edge_score_f32_kernel(
    const float* __restrict__ ph, const float* __restrict__ track_emb,
    const int* __restrict__ esrc, const int* __restrict__ edst,
    float* __restrict__ out, int E) {
  int tid = blockIdx.x * blockDim.x + threadIdx.x;
  int e = tid >> 4, l = tid & 15;
  if (e >= E) return;
  int s = esrc[e], d = edst[e];
  const float4 a = *(const float4*)(ph + (size_t)s * D + l * 4);
  const float4 b = *(const float4*)(track_emb + (size_t)d * D + l * 4);
  float v = a.x * b.x + a.y * b.y + a.z * b.z + a.w * b.w;
  v += __shfl_xor(v, 1, 64);
  v += __shfl_xor(v, 2, 64);
  v += __shfl_xor(v, 4, 64);
  if (l == 0) out[e] = v;
}

extern "C" void kernel_launch(void* const* d_in, const int* in_sizes, int n_in,
                              void* d_out, int out_size, void* d_ws, size_t ws_size,
                              hipStream_t stream) {
  const float* track_emb = (const float*)d_in[0];   // [T, 64] f32
  const int*   edge_src  = (const int*)d_in[1];     // [E]
  const int*   edge_dst  = (const int*)d_in[2];     // [E]
  const int*   sampled   = (const int*)d_in[3];     // [P, 2]
  float* out = (float*)d_out;                       // [E] f32

  const int E = in_sizes[1];
  const int P = in_sizes[3] / 2;
  const int T = in_sizes[0] / D;

  const size_t embq_bytes   = (size_t)T * 16 * sizeof(u32);   // 32 MB
  const size_t escale_bytes = ((size_t)T * sizeof(u16) + 255) & ~(size_t)255; // 1 MB
  const size_t phq_bytes    = (size_t)P * 16 * sizeof(u32);   // 6.4 MB
  const size_t pscale_bytes = (size_t)P * sizeof(u16);        // 0.2 MB

  if (ws_size >= embq_bytes + escale_bytes + phq_bytes + pscale_bytes) {
    char* w = (char*)d_ws;
    u32* embq   = (u32*)w;                        w += embq_bytes;
    u16* escale = (u16*)w;                        w += escale_bytes;
    u32* phq    = (u32*)w;                        w += phq_bytes;
    u16* pscale = (u16*)w;

    // A: quantize track_emb -> int8 + per-row bf16 scale (NT streaming read)
    {
      long t = (long)T * 16;
      int blocks = (int)((t + 255) / 256);
      quant_emb_kernel<<<blocks, 256, 0, stream>>>(track_emb, embq, escale, T);
    }
    // B: build phq (int8) from embq
    {
      long t = (long)P * 4;
      int blocks = (int)((t + 255) / 256);
      ph_build_q8_kernel<<<blocks, 256, 0, stream>>>(embq, escale, sampled,
                                                     phq, pscale, P);
    }
    // C: edge scores
    {
      long t = (long)E * 4;
      int blocks = (int)((t + 255) / 256);
      edge_score_q8q8_kernel<<<blocks, 256, 0, stream>>>(
          phq, pscale, embq, escale, edge_src, edge_dst, out, E);
    }
  } else {
    // fallback: f32 path
    float* ph = (float*)d_ws;
    {
      long t = (long)P * 16;
      int blocks = (int)((t + 255) / 256);
      ph_build_f32_kernel<<<blocks, 256, 0, stream>>>(track_emb, sampled, ph, P);
    }
    {
      long t = (long)E * 16;
      int blocks = (int)((t + 255) / 256);
      edge_score_f32_kernel<<<blocks, 256, 0, stream>>>(ph, track_emb, edge_src,
                                                        edge_dst, out, E);
    }
  }
}